// Round 8
// baseline (44.376 us; speedup 1.0000x reference)
//
#include <hip/hip_runtime.h>

// Projector: out[b,k,d] = sum_l softmax_k( cos(p_k, x[b,l]) ) * x[b,l,d]
// B=4096, L=200, D=64, K=8, fp32.
// v8: one wave per batch (v7) + x-STATIONARY PV: no __shared__ at all.
// Per 8-row step: 2 b128 global loads -> packed-fp32 dots vs raw-proto hoard
// (norms folded) -> octet butterfly (k=c) -> e all-gather (3 DPP + 4 swizzle)
// -> in-register softmax -> 64-VGPR accumulator (slot j <-> k = c^j).
// Cross-lane acc reduction ONCE at the end (split butterfly over row-slot
// bits, xor 8/16/32); lane stores out[k = c ^ bitrev3(a)][chunk c].

#define LQ 200
#define DQ 64
#define KQ 8
#define NSTEP 25   // 25 * 8 rows = 200, no tail

typedef float v2f __attribute__((ext_vector_type(2)));

__device__ __forceinline__ float dppx1(float v) {   // lane ^ 1 (quad_perm [1,0,3,2])
    return __int_as_float(__builtin_amdgcn_update_dpp(0, __float_as_int(v), 0xB1, 0xF, 0xF, true));
}
__device__ __forceinline__ float dppx2(float v) {   // lane ^ 2 (quad_perm [2,3,0,1])
    return __int_as_float(__builtin_amdgcn_update_dpp(0, __float_as_int(v), 0x4E, 0xF, 0xF, true));
}
__device__ __forceinline__ float swz4(float v) {    // lane ^ 4 (ds_swizzle BitMode)
    return __int_as_float(__builtin_amdgcn_ds_swizzle(__float_as_int(v), 0x101F));
}
__device__ __forceinline__ float allred8(float v) { // all-reduce over octet (t&7)
    v += dppx1(v); v += dppx2(v); v += swz4(v); return v;
}
__device__ __forceinline__ v2f fma2(v2f a, v2f b, v2f c) {
    return __builtin_elementwise_fma(a, b, c);      // -> v_pk_fma_f32
}
__device__ __forceinline__ float hsum2(v2f v) { return v.x + v.y; }

// split butterfly over the 8 octet-lanes: s[8] = chunk-partials for all 8 k.
// Returns the full reduction for k == (t&7). (HW-verified v3..v7)
__device__ __forceinline__ float reduce_dots(const float* s, bool b1, bool b2, bool b3) {
    float T0 = (b1 ? s[1] : s[0]) + dppx1(b1 ? s[0] : s[1]);
    float T1 = (b1 ? s[3] : s[2]) + dppx1(b1 ? s[2] : s[3]);
    float T2 = (b1 ? s[5] : s[4]) + dppx1(b1 ? s[4] : s[5]);
    float T3 = (b1 ? s[7] : s[6]) + dppx1(b1 ? s[6] : s[7]);
    float K0 = (b2 ? T1 : T0) + dppx2(b2 ? T0 : T1);
    float K1 = (b2 ? T3 : T2) + dppx2(b2 ? T2 : T3);
    return (b3 ? K1 : K0) + swz4(b3 ? K0 : K1);
}

__global__ __launch_bounds__(64) void projector_kernel(const float* __restrict__ x,
                                                       const float* __restrict__ proto,
                                                       float* __restrict__ out) {
    const int b = blockIdx.x;
    const int t = threadIdx.x;             // one wave
    const int c = t & 7;                   // chunk id = this lane's k after reduce
    const int a = t >> 3;                  // row slot within each 8-row step
    const bool b1 = (c & 1) != 0;
    const bool b2 = (c & 2) != 0;
    const bool b3 = (c & 4) != 0;

    const float4* p4  = (const float4*)proto;
    const float4* xb4 = (const float4*)(x + (size_t)b * (LQ * DQ));

    // ---- raw-proto hoard: 8 k x chunk c (64 VGPR, loaded once, L1 broadcast)
    float4 pA[KQ], pB[KQ];
    #pragma unroll
    for (int k = 0; k < KQ; ++k) {
        pA[k] = p4[k * 16 + 2 * c];
        pB[k] = p4[k * 16 + 2 * c + 1];
    }
    float rnp;   // 1/||p_k|| for k = c (norm folded into score)
    {
        float sp[KQ];
        #pragma unroll
        for (int k = 0; k < KQ; ++k) {
            v2f a0 = {pA[k].x, pA[k].y}, a1 = {pA[k].z, pA[k].w};
            v2f b0 = {pB[k].x, pB[k].y}, b1v = {pB[k].z, pB[k].w};
            v2f t2 = fma2(b1v, b1v, fma2(b0, b0, fma2(a1, a1, a0 * a0)));
            sp[k] = hsum2(t2);
        }
        rnp = __builtin_amdgcn_rsqf(fmaxf(reduce_dots(sp, b1, b2, b3), 1e-12f));
    }

    // acc[j] (4 v2f = 8 floats): partial of out[k = c^j][chunk c]
    v2f acc[KQ][4];
    #pragma unroll
    for (int j = 0; j < KQ; ++j)
        #pragma unroll
        for (int q = 0; q < 4; ++q) acc[j][q] = (v2f){0.f, 0.f};

    // prefetch step 0: row a, chunk c
    float4 f0 = xb4[a * 16 + 2 * c], f1 = xb4[a * 16 + 2 * c + 1];

    #pragma unroll 1
    for (int it = 0; it < NSTEP; ++it) {
        // T14: issue next step's loads (last iter: re-load current, unused)
        const int nrow = (it + 1 < NSTEP ? (it + 1) * 8 : (NSTEP - 1) * 8) + a;
        float4 nf0 = xb4[nrow * 16 + 2 * c];
        float4 nf1 = xb4[nrow * 16 + 2 * c + 1];

        v2f x0 = {f0.x, f0.y}, x1 = {f0.z, f0.w};
        v2f x2 = {f1.x, f1.y}, x3 = {f1.z, f1.w};

        // dots (packed fp32): s[k] = <x_row chunk, p_k chunk>
        float s[KQ];
        #pragma unroll
        for (int k = 0; k < KQ; ++k) {
            v2f pa0 = {pA[k].x, pA[k].y}, pa1 = {pA[k].z, pA[k].w};
            v2f pb0 = {pB[k].x, pB[k].y}, pb1 = {pB[k].z, pB[k].w};
            v2f t2 = fma2(x3, pb1, fma2(x2, pb0, fma2(x1, pa1, x0 * pa0)));
            s[k] = hsum2(t2);
        }
        float d = reduce_dots(s, b1, b2, b3) * rnp;          // raw dot * rn_p, k=c

        v2f q2 = fma2(x3, x3, fma2(x2, x2, fma2(x1, x1, x0 * x0)));
        float sq = allred8(hsum2(q2));                        // row sumsq (all lanes)

        float e0 = __expf(d * __builtin_amdgcn_rsqf(fmaxf(sq, 1e-12f)));
        // octet all-gather: ej = e for k = c^j (3 DPP on VALU + 4 swizzle)
        float e1 = dppx1(e0);
        float e2 = dppx2(e0);
        float e3 = dppx2(e1);
        float e4 = swz4(e0);
        float e5 = swz4(e1);
        float e6 = swz4(e2);
        float e7 = swz4(e3);
        float rd = __builtin_amdgcn_rcpf(((e0 + e1) + (e2 + e3)) + ((e4 + e5) + (e6 + e7)));
        float aj[KQ] = {e0 * rd, e1 * rd, e2 * rd, e3 * rd,
                        e4 * rd, e5 * rd, e6 * rd, e7 * rd};

        // x-stationary PV: acc[j] += a_{c^j} * x (packed fp32, fully in-register)
        #pragma unroll
        for (int j = 0; j < KQ; ++j) {
            v2f aa = {aj[j], aj[j]};
            acc[j][0] = fma2(aa, x0, acc[j][0]);
            acc[j][1] = fma2(aa, x1, acc[j][1]);
            acc[j][2] = fma2(aa, x2, acc[j][2]);
            acc[j][3] = fma2(aa, x3, acc[j][3]);
        }

        f0 = nf0; f1 = nf1;
    }

    // ---- once-per-kernel: split-butterfly reduce over row-slot bits (a)
    // level 1: xor 8
    #pragma unroll
    for (int i = 0; i < 4; ++i)
        #pragma unroll
        for (int q = 0; q < 4; ++q) {
            v2f send = (a & 1) ? acc[i][q] : acc[i + 4][q];
            v2f keep = (a & 1) ? acc[i + 4][q] : acc[i][q];
            v2f r = {__shfl_xor(send.x, 8, 64), __shfl_xor(send.y, 8, 64)};
            acc[i][q] = keep + r;
        }
    // level 2: xor 16
    #pragma unroll
    for (int i = 0; i < 2; ++i)
        #pragma unroll
        for (int q = 0; q < 4; ++q) {
            v2f send = (a & 2) ? acc[i][q] : acc[i + 2][q];
            v2f keep = (a & 2) ? acc[i + 2][q] : acc[i][q];
            v2f r = {__shfl_xor(send.x, 16, 64), __shfl_xor(send.y, 16, 64)};
            acc[i][q] = keep + r;
        }
    // level 3: xor 32
    #pragma unroll
    for (int q = 0; q < 4; ++q) {
        v2f send = (a & 4) ? acc[0][q] : acc[1][q];
        v2f keep = (a & 4) ? acc[1][q] : acc[0][q];
        v2f r = {__shfl_xor(send.x, 32, 64), __shfl_xor(send.y, 32, 64)};
        acc[0][q] = keep + r;
    }

    // lane holds final out[k = c ^ bitrev3(a)][8c..8c+8)
    const int j = ((a & 1) << 2) | (a & 2) | ((a & 4) >> 2);
    const int k = c ^ j;
    float4* og = (float4*)(out + (size_t)b * (KQ * DQ));
    og[k * 16 + 2 * c]     = make_float4(acc[0][0].x, acc[0][0].y, acc[0][1].x, acc[0][1].y);
    og[k * 16 + 2 * c + 1] = make_float4(acc[0][2].x, acc[0][2].y, acc[0][3].x, acc[0][3].y);
}

extern "C" void kernel_launch(void* const* d_in, const int* in_sizes, int n_in,
                              void* d_out, int out_size, void* d_ws, size_t ws_size,
                              hipStream_t stream) {
    const float* x     = (const float*)d_in[0];   // [B, L, D] fp32
    const float* proto = (const float*)d_in[1];   // [K, D] fp32
    float* out = (float*)d_out;                   // [B, K, D] fp32

    const int Bn = in_sizes[0] / (LQ * DQ);       // 4096

    projector_kernel<<<Bn, 64, 0, stream>>>(x, proto, out);
}

// Round 10
// 43.541 us; speedup vs baseline: 1.0192x; 1.0192x over previous
//
#include <hip/hip_runtime.h>

// Projector: out[b,k,d] = sum_l softmax_k( cos(p_k, x[b,l]) ) * x[b,l,d]
// B=4096, L=200, D=64, K=8, fp32.
// v10 = v9 with the xor4 DPP direction bug fixed:
//   row_shr:N -> source lane n-N ; row_shl:N -> source lane n+N  (GPUOpen scan idiom)
//   banks 0,2 (n&4==0, mask 0x5) need n+4 -> row_shl:4
//   banks 1,3 (n&4==4, mask 0xA) need n-4 -> row_shr:4
// Structure: one wave per batch, x-stationary PV, zero LDS in the loop,
// depth-3 software pipeline (4 rotating staging sets), packed-fp32 math.

#define LQ 200
#define DQ 64
#define KQ 8
#define NSTEP 25   // 25 * 8 rows = 200, no tail

typedef float v2f __attribute__((ext_vector_type(2)));

__device__ __forceinline__ float dppx1(float v) {   // lane ^ 1 (quad_perm [1,0,3,2])
    return __int_as_float(__builtin_amdgcn_update_dpp(0, __float_as_int(v), 0xB1, 0xF, 0xF, true));
}
__device__ __forceinline__ float dppx2(float v) {   // lane ^ 2 (quad_perm [2,3,0,1])
    return __int_as_float(__builtin_amdgcn_update_dpp(0, __float_as_int(v), 0x4E, 0xF, 0xF, true));
}
// lane ^ 4, pure VALU (fixed): row_shl:4 feeds banks 0,2 (mask 0x5) with lane n+4;
// row_shr:4 feeds banks 1,3 (mask 0xA) with lane n-4; chained via DPP 'old'.
__device__ __forceinline__ float xor4(float v) {
    int vi = __float_as_int(v);
    int r1 = __builtin_amdgcn_update_dpp(0,  vi, 0x104, 0xF, 0x5, false);  // row_shl:4 -> banks 0,2
    int r  = __builtin_amdgcn_update_dpp(r1, vi, 0x114, 0xF, 0xA, false);  // row_shr:4 -> banks 1,3
    return __int_as_float(r);
}
__device__ __forceinline__ float allred8(float v) { // all-reduce over octet (t&7)
    v += dppx1(v); v += dppx2(v); v += xor4(v); return v;
}
__device__ __forceinline__ v2f fma2(v2f a, v2f b, v2f c) {
    return __builtin_elementwise_fma(a, b, c);      // -> v_pk_fma_f32
}
__device__ __forceinline__ float hsum2(v2f v) { return v.x + v.y; }

// split butterfly over the 8 octet-lanes: s[8] = chunk-partials for all 8 k.
// Returns the full reduction for k == (t&7). (HW-verified v3..v8 with swz4;
// xor4 now implements the same lane^4 exchange on the VALU.)
__device__ __forceinline__ float reduce_dots(const float* s, bool b1, bool b2, bool b3) {
    float T0 = (b1 ? s[1] : s[0]) + dppx1(b1 ? s[0] : s[1]);
    float T1 = (b1 ? s[3] : s[2]) + dppx1(b1 ? s[2] : s[3]);
    float T2 = (b1 ? s[5] : s[4]) + dppx1(b1 ? s[4] : s[5]);
    float T3 = (b1 ? s[7] : s[6]) + dppx1(b1 ? s[6] : s[7]);
    float K0 = (b2 ? T1 : T0) + dppx2(b2 ? T0 : T1);
    float K1 = (b2 ? T3 : T2) + dppx2(b2 ? T2 : T3);
    return (b3 ? K1 : K0) + xor4(b3 ? K0 : K1);
}

struct Ctx {
    float4 pA[KQ], pB[KQ];
    float rnp;
    bool b1, b2, b3;
};

// one 8-row step: dots -> butterfly -> softmax -> x-stationary PV
__device__ __forceinline__ void step_compute(float4 f0, float4 f1,
                                             const Ctx& cx, v2f (&acc)[KQ][4]) {
    v2f x0 = {f0.x, f0.y}, x1 = {f0.z, f0.w};
    v2f x2 = {f1.x, f1.y}, x3 = {f1.z, f1.w};

    float s[KQ];
    #pragma unroll
    for (int k = 0; k < KQ; ++k) {
        v2f pa0 = {cx.pA[k].x, cx.pA[k].y}, pa1 = {cx.pA[k].z, cx.pA[k].w};
        v2f pb0 = {cx.pB[k].x, cx.pB[k].y}, pb1 = {cx.pB[k].z, cx.pB[k].w};
        v2f t2 = fma2(x3, pb1, fma2(x2, pb0, fma2(x1, pa1, x0 * pa0)));
        s[k] = hsum2(t2);
    }
    float d = reduce_dots(s, cx.b1, cx.b2, cx.b3) * cx.rnp;   // raw dot * rn_p, k=c

    v2f q2 = fma2(x3, x3, fma2(x2, x2, fma2(x1, x1, x0 * x0)));
    float sq = allred8(hsum2(q2));                             // row sumsq

    float e0 = __expf(d * __builtin_amdgcn_rsqf(fmaxf(sq, 1e-12f)));
    // octet all-gather: ej = e of k = c^j (3 DPP + 4 xor4, all VALU)
    float e1 = dppx1(e0);
    float e2 = dppx2(e0);
    float e3 = dppx2(e1);
    float e4 = xor4(e0);
    float e5 = xor4(e1);
    float e6 = xor4(e2);
    float e7 = xor4(e3);
    float rd = __builtin_amdgcn_rcpf(((e0 + e1) + (e2 + e3)) + ((e4 + e5) + (e6 + e7)));
    float aj[KQ] = {e0 * rd, e1 * rd, e2 * rd, e3 * rd,
                    e4 * rd, e5 * rd, e6 * rd, e7 * rd};

    #pragma unroll
    for (int j = 0; j < KQ; ++j) {
        v2f aa = {aj[j], aj[j]};
        acc[j][0] = fma2(aa, x0, acc[j][0]);
        acc[j][1] = fma2(aa, x1, acc[j][1]);
        acc[j][2] = fma2(aa, x2, acc[j][2]);
        acc[j][3] = fma2(aa, x3, acc[j][3]);
    }
}

__global__ __launch_bounds__(64, 2) void projector_kernel(const float* __restrict__ x,
                                                          const float* __restrict__ proto,
                                                          float* __restrict__ out) {
    const int b = blockIdx.x;
    const int t = threadIdx.x;             // one wave
    const int c = t & 7;                   // chunk id = this lane's k after reduce
    const int a = t >> 3;                  // row slot within each 8-row step

    Ctx cx;
    cx.b1 = (c & 1) != 0;
    cx.b2 = (c & 2) != 0;
    cx.b3 = (c & 4) != 0;

    const float4* p4  = (const float4*)proto;
    const float4* xb4 = (const float4*)(x + (size_t)b * (LQ * DQ));

    // raw-proto hoard: 8 k x chunk c (64 VGPR, loaded once, L1 broadcast)
    #pragma unroll
    for (int k = 0; k < KQ; ++k) {
        cx.pA[k] = p4[k * 16 + 2 * c];
        cx.pB[k] = p4[k * 16 + 2 * c + 1];
    }
    {
        float sp[KQ];
        #pragma unroll
        for (int k = 0; k < KQ; ++k) {
            v2f a0 = {cx.pA[k].x, cx.pA[k].y}, a1 = {cx.pA[k].z, cx.pA[k].w};
            v2f b0 = {cx.pB[k].x, cx.pB[k].y}, b1v = {cx.pB[k].z, cx.pB[k].w};
            sp[k] = hsum2(fma2(b1v, b1v, fma2(b0, b0, fma2(a1, a1, a0 * a0))));
        }
        cx.rnp = __builtin_amdgcn_rsqf(fmaxf(reduce_dots(sp, cx.b1, cx.b2, cx.b3), 1e-12f));
    }

    v2f acc[KQ][4];
    #pragma unroll
    for (int j = 0; j < KQ; ++j)
        #pragma unroll
        for (int q = 0; q < 4; ++q) acc[j][q] = (v2f){0.f, 0.f};

    const int lofs = a * 16 + 2 * c;       // lane's float4 offset within a step row-block

    // depth-3 software pipeline: 4 staging sets, loads i+1..i+4 in flight
    float4 s0a = xb4[0 * 128 + lofs], s0b = xb4[0 * 128 + lofs + 1];
    float4 s1a = xb4[1 * 128 + lofs], s1b = xb4[1 * 128 + lofs + 1];
    float4 s2a = xb4[2 * 128 + lofs], s2b = xb4[2 * 128 + lofs + 1];
    float4 s3a = xb4[3 * 128 + lofs], s3b = xb4[3 * 128 + lofs + 1];

    #pragma unroll 1
    for (int g = 0; g < 6; ++g) {          // steps 4g .. 4g+3; step 24 in epilogue
        const int base = 4 * g;
        {
            const int sn = (base + 4 < NSTEP) ? base + 4 : NSTEP - 1;
            float4 na = xb4[sn * 128 + lofs], nb = xb4[sn * 128 + lofs + 1];
            step_compute(s0a, s0b, cx, acc);
            s0a = na; s0b = nb;
        }
        {
            const int sn = (base + 5 < NSTEP) ? base + 5 : NSTEP - 1;
            float4 na = xb4[sn * 128 + lofs], nb = xb4[sn * 128 + lofs + 1];
            step_compute(s1a, s1b, cx, acc);
            s1a = na; s1b = nb;
        }
        {
            const int sn = (base + 6 < NSTEP) ? base + 6 : NSTEP - 1;
            float4 na = xb4[sn * 128 + lofs], nb = xb4[sn * 128 + lofs + 1];
            step_compute(s2a, s2b, cx, acc);
            s2a = na; s2b = nb;
        }
        {
            const int sn = (base + 7 < NSTEP) ? base + 7 : NSTEP - 1;
            float4 na = xb4[sn * 128 + lofs], nb = xb4[sn * 128 + lofs + 1];
            step_compute(s3a, s3b, cx, acc);
            s3a = na; s3b = nb;
        }
    }
    step_compute(s0a, s0b, cx, acc);       // step 24

    // ---- once-per-kernel: split-butterfly reduce over row-slot bits (a)
    #pragma unroll
    for (int i = 0; i < 4; ++i)
        #pragma unroll
        for (int q = 0; q < 4; ++q) {
            v2f send = (a & 1) ? acc[i][q] : acc[i + 4][q];
            v2f keep = (a & 1) ? acc[i + 4][q] : acc[i][q];
            v2f r = {__shfl_xor(send.x, 8, 64), __shfl_xor(send.y, 8, 64)};
            acc[i][q] = keep + r;
        }
    #pragma unroll
    for (int i = 0; i < 2; ++i)
        #pragma unroll
        for (int q = 0; q < 4; ++q) {
            v2f send = (a & 2) ? acc[i][q] : acc[i + 2][q];
            v2f keep = (a & 2) ? acc[i + 2][q] : acc[i][q];
            v2f r = {__shfl_xor(send.x, 16, 64), __shfl_xor(send.y, 16, 64)};
            acc[i][q] = keep + r;
        }
    #pragma unroll
    for (int q = 0; q < 4; ++q) {
        v2f send = (a & 4) ? acc[0][q] : acc[1][q];
        v2f keep = (a & 4) ? acc[1][q] : acc[0][q];
        v2f r = {__shfl_xor(send.x, 32, 64), __shfl_xor(send.y, 32, 64)};
        acc[0][q] = keep + r;
    }

    // lane holds final out[k = c ^ bitrev3(a)][8c..8c+8)
    const int j = ((a & 1) << 2) | (a & 2) | ((a & 4) >> 2);
    const int k = c ^ j;
    float4* og = (float4*)(out + (size_t)b * (KQ * DQ));
    og[k * 16 + 2 * c]     = make_float4(acc[0][0].x, acc[0][0].y, acc[0][1].x, acc[0][1].y);
    og[k * 16 + 2 * c + 1] = make_float4(acc[0][2].x, acc[0][2].y, acc[0][3].x, acc[0][3].y);
}

extern "C" void kernel_launch(void* const* d_in, const int* in_sizes, int n_in,
                              void* d_out, int out_size, void* d_ws, size_t ws_size,
                              hipStream_t stream) {
    const float* x     = (const float*)d_in[0];   // [B, L, D] fp32
    const float* proto = (const float*)d_in[1];   // [K, D] fp32
    float* out = (float*)d_out;                   // [B, K, D] fp32

    const int Bn = in_sizes[0] / (LQ * DQ);       // 4096

    projector_kernel<<<Bn, 64, 0, stream>>>(x, proto, out);
}

// Round 11
// 41.587 us; speedup vs baseline: 1.0671x; 1.0470x over previous
//
#include <hip/hip_runtime.h>

// Projector: out[b,k,d] = sum_l softmax_k( cos(p_k, x[b,l]) ) * x[b,l,d]
// B=4096, L=200, D=64, K=8, fp32.
// v11 = v10 + TWO BATCHES PER WAVE (grid 2048 -> 8 waves/CU, ONE occupancy
// round instead of two). Batch 1's staging loads issue before batch 0's
// butterfly+store epilogue, hiding the second pipeline fill under VALU.
// Unchanged from v10: one wave per batch-stream, x-stationary PV, zero LDS
// in the loop, all-VALU cross-lane (DPP xor4), packed-fp32, depth-3 pipeline.

#define LQ 200
#define DQ 64
#define KQ 8
#define NSTEP 25   // 25 * 8 rows = 200, no tail

typedef float v2f __attribute__((ext_vector_type(2)));

__device__ __forceinline__ float dppx1(float v) {   // lane ^ 1 (quad_perm [1,0,3,2])
    return __int_as_float(__builtin_amdgcn_update_dpp(0, __float_as_int(v), 0xB1, 0xF, 0xF, true));
}
__device__ __forceinline__ float dppx2(float v) {   // lane ^ 2 (quad_perm [2,3,0,1])
    return __int_as_float(__builtin_amdgcn_update_dpp(0, __float_as_int(v), 0x4E, 0xF, 0xF, true));
}
// lane ^ 4, pure VALU: row_shl:4 feeds lanes n&4==0 (banks 0,2, mask 0x5) with
// lane n+4; row_shr:4 feeds lanes n&4==4 (banks 1,3, mask 0xA) with lane n-4.
// (HW-verified in v10)
__device__ __forceinline__ float xor4(float v) {
    int vi = __float_as_int(v);
    int r1 = __builtin_amdgcn_update_dpp(0,  vi, 0x104, 0xF, 0x5, false);  // row_shl:4
    int r  = __builtin_amdgcn_update_dpp(r1, vi, 0x114, 0xF, 0xA, false);  // row_shr:4
    return __int_as_float(r);
}
__device__ __forceinline__ float allred8(float v) { // all-reduce over octet (t&7)
    v += dppx1(v); v += dppx2(v); v += xor4(v); return v;
}
__device__ __forceinline__ v2f fma2(v2f a, v2f b, v2f c) {
    return __builtin_elementwise_fma(a, b, c);      // -> v_pk_fma_f32
}
__device__ __forceinline__ float hsum2(v2f v) { return v.x + v.y; }

// split butterfly over the 8 octet-lanes: s[8] = chunk-partials for all 8 k.
// Returns the full reduction for k == (t&7). (HW-verified v3..v10)
__device__ __forceinline__ float reduce_dots(const float* s, bool b1, bool b2, bool b3) {
    float T0 = (b1 ? s[1] : s[0]) + dppx1(b1 ? s[0] : s[1]);
    float T1 = (b1 ? s[3] : s[2]) + dppx1(b1 ? s[2] : s[3]);
    float T2 = (b1 ? s[5] : s[4]) + dppx1(b1 ? s[4] : s[5]);
    float T3 = (b1 ? s[7] : s[6]) + dppx1(b1 ? s[6] : s[7]);
    float K0 = (b2 ? T1 : T0) + dppx2(b2 ? T0 : T1);
    float K1 = (b2 ? T3 : T2) + dppx2(b2 ? T2 : T3);
    return (b3 ? K1 : K0) + xor4(b3 ? K0 : K1);
}

struct Ctx {
    float4 pA[KQ], pB[KQ];
    float rnp;
    bool b1, b2, b3;
};

// one 8-row step: dots -> butterfly -> softmax -> x-stationary PV
__device__ __forceinline__ void step_compute(float4 f0, float4 f1,
                                             const Ctx& cx, v2f (&acc)[KQ][4]) {
    v2f x0 = {f0.x, f0.y}, x1 = {f0.z, f0.w};
    v2f x2 = {f1.x, f1.y}, x3 = {f1.z, f1.w};

    float s[KQ];
    #pragma unroll
    for (int k = 0; k < KQ; ++k) {
        v2f pa0 = {cx.pA[k].x, cx.pA[k].y}, pa1 = {cx.pA[k].z, cx.pA[k].w};
        v2f pb0 = {cx.pB[k].x, cx.pB[k].y}, pb1 = {cx.pB[k].z, cx.pB[k].w};
        v2f t2 = fma2(x3, pb1, fma2(x2, pb0, fma2(x1, pa1, x0 * pa0)));
        s[k] = hsum2(t2);
    }
    float d = reduce_dots(s, cx.b1, cx.b2, cx.b3) * cx.rnp;   // raw dot * rn_p, k=c

    v2f q2 = fma2(x3, x3, fma2(x2, x2, fma2(x1, x1, x0 * x0)));
    float sq = allred8(hsum2(q2));                             // row sumsq

    float e0 = __expf(d * __builtin_amdgcn_rsqf(fmaxf(sq, 1e-12f)));
    // octet all-gather: ej = e of k = c^j (3 DPP + 4 xor4, all VALU)
    float e1 = dppx1(e0);
    float e2 = dppx2(e0);
    float e3 = dppx2(e1);
    float e4 = xor4(e0);
    float e5 = xor4(e1);
    float e6 = xor4(e2);
    float e7 = xor4(e3);
    float rd = __builtin_amdgcn_rcpf(((e0 + e1) + (e2 + e3)) + ((e4 + e5) + (e6 + e7)));
    float aj[KQ] = {e0 * rd, e1 * rd, e2 * rd, e3 * rd,
                    e4 * rd, e5 * rd, e6 * rd, e7 * rd};

    #pragma unroll
    for (int j = 0; j < KQ; ++j) {
        v2f aa = {aj[j], aj[j]};
        acc[j][0] = fma2(aa, x0, acc[j][0]);
        acc[j][1] = fma2(aa, x1, acc[j][1]);
        acc[j][2] = fma2(aa, x2, acc[j][2]);
        acc[j][3] = fma2(aa, x3, acc[j][3]);
    }
}

__global__ __launch_bounds__(64, 2) void projector_kernel(const float* __restrict__ x,
                                                          const float* __restrict__ proto,
                                                          float* __restrict__ out) {
    const int bid = blockIdx.x;            // handles batches 2*bid and 2*bid+1
    const int t = threadIdx.x;             // one wave
    const int c = t & 7;                   // chunk id = this lane's k after reduce
    const int a = t >> 3;                  // row slot within each 8-row step

    Ctx cx;
    cx.b1 = (c & 1) != 0;
    cx.b2 = (c & 2) != 0;
    cx.b3 = (c & 4) != 0;

    const float4* p4 = (const float4*)proto;

    // raw-proto hoard: 8 k x chunk c (64 VGPR, loaded once, L1 broadcast)
    #pragma unroll
    for (int k = 0; k < KQ; ++k) {
        cx.pA[k] = p4[k * 16 + 2 * c];
        cx.pB[k] = p4[k * 16 + 2 * c + 1];
    }
    {
        float sp[KQ];
        #pragma unroll
        for (int k = 0; k < KQ; ++k) {
            v2f a0 = {cx.pA[k].x, cx.pA[k].y}, a1 = {cx.pA[k].z, cx.pA[k].w};
            v2f b0 = {cx.pB[k].x, cx.pB[k].y}, b1v = {cx.pB[k].z, cx.pB[k].w};
            sp[k] = hsum2(fma2(b1v, b1v, fma2(b0, b0, fma2(a1, a1, a0 * a0))));
        }
        cx.rnp = __builtin_amdgcn_rsqf(fmaxf(reduce_dots(sp, cx.b1, cx.b2, cx.b3), 1e-12f));
    }

    const int lofs = a * 16 + 2 * c;       // lane's float4 offset within a step row-block

    // prologue: fill the 4 staging sets from batch 2*bid
    const float4* xb4 = (const float4*)(x + (size_t)(2 * bid) * (LQ * DQ));
    float4 s0a = xb4[0 * 128 + lofs], s0b = xb4[0 * 128 + lofs + 1];
    float4 s1a = xb4[1 * 128 + lofs], s1b = xb4[1 * 128 + lofs + 1];
    float4 s2a = xb4[2 * 128 + lofs], s2b = xb4[2 * 128 + lofs + 1];
    float4 s3a = xb4[3 * 128 + lofs], s3b = xb4[3 * 128 + lofs + 1];

    #pragma unroll 1
    for (int half = 0; half < 2; ++half) {
        const size_t b = 2 * (size_t)bid + half;

        v2f acc[KQ][4];
        #pragma unroll
        for (int j = 0; j < KQ; ++j)
            #pragma unroll
            for (int q = 0; q < 4; ++q) acc[j][q] = (v2f){0.f, 0.f};

        // main loop: steps 0..23, depth-3 prefetch (clamped at stream end)
        #pragma unroll 1
        for (int g = 0; g < 6; ++g) {
            const int base = 4 * g;
            {
                const int sn = (base + 4 < NSTEP) ? base + 4 : NSTEP - 1;
                float4 na = xb4[sn * 128 + lofs], nb = xb4[sn * 128 + lofs + 1];
                step_compute(s0a, s0b, cx, acc);
                s0a = na; s0b = nb;
            }
            {
                const int sn = (base + 5 < NSTEP) ? base + 5 : NSTEP - 1;
                float4 na = xb4[sn * 128 + lofs], nb = xb4[sn * 128 + lofs + 1];
                step_compute(s1a, s1b, cx, acc);
                s1a = na; s1b = nb;
            }
            {
                const int sn = (base + 6 < NSTEP) ? base + 6 : NSTEP - 1;
                float4 na = xb4[sn * 128 + lofs], nb = xb4[sn * 128 + lofs + 1];
                step_compute(s2a, s2b, cx, acc);
                s2a = na; s2b = nb;
            }
            {
                const int sn = (base + 7 < NSTEP) ? base + 7 : NSTEP - 1;
                float4 na = xb4[sn * 128 + lofs], nb = xb4[sn * 128 + lofs + 1];
                step_compute(s3a, s3b, cx, acc);
                s3a = na; s3b = nb;
            }
        }
        step_compute(s0a, s0b, cx, acc);   // step 24

        // issue NEXT batch's staging loads before the epilogue butterfly,
        // so the refill latency hides under ~70 VALU instructions + store.
        if (half == 0) {
            xb4 = (const float4*)(x + (size_t)(2 * bid + 1) * (LQ * DQ));
            s0a = xb4[0 * 128 + lofs]; s0b = xb4[0 * 128 + lofs + 1];
            s1a = xb4[1 * 128 + lofs]; s1b = xb4[1 * 128 + lofs + 1];
            s2a = xb4[2 * 128 + lofs]; s2b = xb4[2 * 128 + lofs + 1];
            s3a = xb4[3 * 128 + lofs]; s3b = xb4[3 * 128 + lofs + 1];
        }

        // ---- split-butterfly reduce over row-slot bits (a)
        #pragma unroll
        for (int i = 0; i < 4; ++i)
            #pragma unroll
            for (int q = 0; q < 4; ++q) {
                v2f send = (a & 1) ? acc[i][q] : acc[i + 4][q];
                v2f keep = (a & 1) ? acc[i + 4][q] : acc[i][q];
                v2f r = {__shfl_xor(send.x, 8, 64), __shfl_xor(send.y, 8, 64)};
                acc[i][q] = keep + r;
            }
        #pragma unroll
        for (int i = 0; i < 2; ++i)
            #pragma unroll
            for (int q = 0; q < 4; ++q) {
                v2f send = (a & 2) ? acc[i][q] : acc[i + 2][q];
                v2f keep = (a & 2) ? acc[i + 2][q] : acc[i][q];
                v2f r = {__shfl_xor(send.x, 16, 64), __shfl_xor(send.y, 16, 64)};
                acc[i][q] = keep + r;
            }
        #pragma unroll
        for (int q = 0; q < 4; ++q) {
            v2f send = (a & 4) ? acc[0][q] : acc[1][q];
            v2f keep = (a & 4) ? acc[1][q] : acc[0][q];
            v2f r = {__shfl_xor(send.x, 32, 64), __shfl_xor(send.y, 32, 64)};
            acc[0][q] = keep + r;
        }

        // lane holds final out[k = c ^ bitrev3(a)][8c..8c+8)
        const int j = ((a & 1) << 2) | (a & 2) | ((a & 4) >> 2);
        const int k = c ^ j;
        float4* og = (float4*)(out + b * (KQ * DQ));
        og[k * 16 + 2 * c]     = make_float4(acc[0][0].x, acc[0][0].y, acc[0][1].x, acc[0][1].y);
        og[k * 16 + 2 * c + 1] = make_float4(acc[0][2].x, acc[0][2].y, acc[0][3].x, acc[0][3].y);
    }
}

extern "C" void kernel_launch(void* const* d_in, const int* in_sizes, int n_in,
                              void* d_out, int out_size, void* d_ws, size_t ws_size,
                              hipStream_t stream) {
    const float* x     = (const float*)d_in[0];   // [B, L, D] fp32
    const float* proto = (const float*)d_in[1];   // [K, D] fp32
    float* out = (float*)d_out;                   // [B, K, D] fp32

    const int Bn = in_sizes[0] / (LQ * DQ);       // 4096

    projector_kernel<<<Bn / 2, 64, 0, stream>>>(x, proto, out);
}